// Round 2
// baseline (11549.408 us; speedup 1.0000x reference)
//
#include <hip/hip_runtime.h>

#define N 8192
#define DIM 64
#define BIGF 1e30f

// ---------------- kernel 0: zero the output buffer (births stay 0) -------------
__global__ void zero_out_kernel(float* __restrict__ out, int n) {
    int i = blockIdx.x * blockDim.x + threadIdx.x;
    if (i < n) out[i] = 0.0f;
}

// ---------------- kernel B: fp32 distance matrix, 64x64 tiles ------------------
// D[i][j] = sqrt(max(n_i + n_j - 2*dot(x_i,x_j), 0)) stored as fp32.
// Norms are computed in-kernel from the LDS tiles (no extra ws buffer).
__global__ __launch_bounds__(256) void dist_kernel(const float* __restrict__ x,
                                                   float* __restrict__ dmat) {
    __shared__ float As[DIM][64];   // [k][i] layout -> vector reads in inner loop
    __shared__ float Bs[DIM][64];
    const int bi = blockIdx.y, bj = blockIdx.x;
    const int t  = threadIdx.x;

    // Stage: each thread loads 16 floats of one row (row = t>>2, 16-col chunk).
    {
        int r  = t >> 2;
        int c0 = (t & 3) * 16;
        const float4* pa = (const float4*)(x + (size_t)(bi * 64 + r) * DIM + c0);
        const float4* pb = (const float4*)(x + (size_t)(bj * 64 + r) * DIM + c0);
        #pragma unroll
        for (int q = 0; q < 4; q++) {
            float4 a = pa[q], b = pb[q];
            int c = c0 + q * 4;
            As[c + 0][r] = a.x; As[c + 1][r] = a.y; As[c + 2][r] = a.z; As[c + 3][r] = a.w;
            Bs[c + 0][r] = b.x; Bs[c + 1][r] = b.y; Bs[c + 2][r] = b.z; Bs[c + 3][r] = b.w;
        }
    }
    __syncthreads();

    const int tx = t & 15, ty = t >> 4;   // 16x16 threads, 4x4 outputs each
    float acc[4][4] = {};
    float ni[4] = {}, nj[4] = {};
    #pragma unroll 4
    for (int k = 0; k < DIM; k++) {
        float4 a = *(const float4*)&As[k][ty * 4];
        float4 b = *(const float4*)&Bs[k][tx * 4];
        float av[4] = {a.x, a.y, a.z, a.w};
        float bv[4] = {b.x, b.y, b.z, b.w};
        #pragma unroll
        for (int r = 0; r < 4; r++)
            #pragma unroll
            for (int c = 0; c < 4; c++)
                acc[r][c] += av[r] * bv[c];
        #pragma unroll
        for (int r = 0; r < 4; r++) ni[r] += av[r] * av[r];
        #pragma unroll
        for (int c = 0; c < 4; c++) nj[c] += bv[c] * bv[c];
    }

    #pragma unroll
    for (int r = 0; r < 4; r++) {
        int gi = bi * 64 + ty * 4 + r;
        float4 o;
        float od[4];
        #pragma unroll
        for (int c = 0; c < 4; c++) {
            float d2 = ni[r] + nj[c] - 2.0f * acc[r][c];
            d2 = d2 < 0.0f ? 0.0f : d2;
            od[c] = sqrtf(d2);
        }
        o.x = od[0]; o.y = od[1]; o.z = od[2]; o.w = od[3];
        *(float4*)(dmat + (size_t)gi * N + bj * 64 + tx * 4) = o;
    }
}

// ---------------- kernel C: sequential Prim, one workgroup ---------------------
// mind[] lives in registers (8 entries/thread). Per step: packed-u64 argmin
// ((f32bits<<32)|idx -> min = smallest value, ties -> smallest index, matching
// jnp.argmin first-occurrence), ONE barrier via parity-double-buffered LDS.
__device__ inline unsigned long long shfl_down_u64(unsigned long long p, int off) {
    unsigned hi = (unsigned)(p >> 32), lo = (unsigned)p;
    hi = __shfl_down(hi, off, 64);
    lo = __shfl_down(lo, off, 64);
    return ((unsigned long long)hi << 32) | lo;
}

__global__ __launch_bounds__(1024) void prim_kernel(const float* __restrict__ dmat,
                                                    float* __restrict__ out) {
    const int t    = threadIdx.x;
    const int lane = t & 63;
    const int wave = t >> 6;
    __shared__ unsigned long long red[2][16];

    float mind[8];
    {   // init from row 0 (two 16B loads per thread)
        float4 r0 = *(const float4*)(dmat + t * 8);
        float4 r1 = *(const float4*)(dmat + t * 8 + 4);
        mind[0] = r0.x; mind[1] = r0.y; mind[2] = r0.z; mind[3] = r0.w;
        mind[4] = r1.x; mind[5] = r1.y; mind[6] = r1.z; mind[7] = r1.w;
    }
    unsigned mask = (t == 0) ? 1u : 0u;   // vertex 0 starts in the tree

    for (int step = 0; step < N - 1; ++step) {
        // local argmin over this thread's 8 masked entries
        unsigned long long p = ~0ull;
        #pragma unroll
        for (int k = 0; k < 8; k++) {
            float v = ((mask >> k) & 1u) ? BIGF : mind[k];
            unsigned long long q =
                ((unsigned long long)__float_as_uint(v) << 32) | (unsigned)(t * 8 + k);
            p = q < p ? q : p;
        }
        // wave reduction (64 lanes)
        #pragma unroll
        for (int off = 32; off; off >>= 1) {
            unsigned long long q = shfl_down_u64(p, off);
            p = q < p ? q : p;
        }
        if (lane == 0) red[step & 1][wave] = p;
        __syncthreads();
        // every thread reduces the 16 wave minima (no second barrier needed:
        // next step writes the other parity buffer)
        unsigned long long m = red[step & 1][0];
        #pragma unroll
        for (int w = 1; w < 16; w++) {
            unsigned long long q = red[step & 1][w];
            m = q < m ? q : m;
        }
        int j = (int)(unsigned)m;
        if (t == 0) out[2 * step + 1] = __uint_as_float((unsigned)(m >> 32));
        if ((j >> 3) == t) mask |= 1u << (j & 7);

        // mind = min(mind, dist[j])  (masked entries stay masked at pack time)
        const float* row = dmat + (size_t)j * N + t * 8;
        float4 r0 = *(const float4*)(row);
        float4 r1 = *(const float4*)(row + 4);
        float dv[8] = {r0.x, r0.y, r0.z, r0.w, r1.x, r1.y, r1.z, r1.w};
        #pragma unroll
        for (int k = 0; k < 8; k++) {
            mind[k] = dv[k] < mind[k] ? dv[k] : mind[k];
        }
    }
}

extern "C" void kernel_launch(void* const* d_in, const int* in_sizes, int n_in,
                              void* d_out, int out_size, void* d_ws, size_t ws_size,
                              hipStream_t stream) {
    const float* x = (const float*)d_in[0];
    float* out = (float*)d_out;

    float* dmat = (float*)d_ws;   // 8192*8192*4 = 256 MiB

    zero_out_kernel<<<(out_size + 255) / 256, 256, 0, stream>>>(out, out_size);
    dist_kernel<<<dim3(N / 64, N / 64), 256, 0, stream>>>(x, dmat);
    prim_kernel<<<1, 1024, 0, stream>>>(dmat, out);
}

// Round 5
// 11486.707 us; speedup vs baseline: 1.0055x; 1.0055x over previous
//
#include <hip/hip_runtime.h>

#define N 8192
#define DIM 64
#define BIGF 1e30f
#define CAP_E 500000

typedef unsigned long long u64;
typedef unsigned int u32;
typedef unsigned short u16;

// ---------------- zero the output buffer (births stay 0) -----------------------
__global__ void zero_out_kernel(float* __restrict__ out, int n) {
    int i = blockIdx.x * blockDim.x + threadIdx.x;
    if (i < n) out[i] = 0.0f;
}

// ---------------- fp32 distance matrix, 64x64 tiles (bitwise-identical to R2) --
__global__ __launch_bounds__(256) void dist_kernel(const float* __restrict__ x,
                                                   float* __restrict__ dmat) {
    __shared__ float As[DIM][64];
    __shared__ float Bs[DIM][64];
    const int bi = blockIdx.y, bj = blockIdx.x;
    const int t  = threadIdx.x;
    {
        int r  = t >> 2;
        int c0 = (t & 3) * 16;
        const float4* pa = (const float4*)(x + (size_t)(bi * 64 + r) * DIM + c0);
        const float4* pb = (const float4*)(x + (size_t)(bj * 64 + r) * DIM + c0);
        #pragma unroll
        for (int q = 0; q < 4; q++) {
            float4 a = pa[q], b = pb[q];
            int c = c0 + q * 4;
            As[c + 0][r] = a.x; As[c + 1][r] = a.y; As[c + 2][r] = a.z; As[c + 3][r] = a.w;
            Bs[c + 0][r] = b.x; Bs[c + 1][r] = b.y; Bs[c + 2][r] = b.z; Bs[c + 3][r] = b.w;
        }
    }
    __syncthreads();

    const int tx = t & 15, ty = t >> 4;
    float acc[4][4] = {};
    float ni[4] = {}, nj[4] = {};
    #pragma unroll 4
    for (int k = 0; k < DIM; k++) {
        float4 a = *(const float4*)&As[k][ty * 4];
        float4 b = *(const float4*)&Bs[k][tx * 4];
        float av[4] = {a.x, a.y, a.z, a.w};
        float bv[4] = {b.x, b.y, b.z, b.w};
        #pragma unroll
        for (int r = 0; r < 4; r++)
            #pragma unroll
            for (int c = 0; c < 4; c++)
                acc[r][c] += av[r] * bv[c];
        #pragma unroll
        for (int r = 0; r < 4; r++) ni[r] += av[r] * av[r];
        #pragma unroll
        for (int c = 0; c < 4; c++) nj[c] += bv[c] * bv[c];
    }

    #pragma unroll
    for (int r = 0; r < 4; r++) {
        int gi = bi * 64 + ty * 4 + r;
        float od[4];
        #pragma unroll
        for (int c = 0; c < 4; c++) {
            float d2 = ni[r] + nj[c] - 2.0f * acc[r][c];
            d2 = d2 < 0.0f ? 0.0f : d2;
            od[c] = sqrtf(d2);
        }
        float4 o; o.x = od[0]; o.y = od[1]; o.z = od[2]; o.w = od[3];
        *(float4*)(dmat + (size_t)gi * N + bj * 64 + tx * 4) = o;
    }
}

__device__ inline u64 shfl_down_u64(u64 p, int off) {
    unsigned hi = (unsigned)(p >> 32), lo = (unsigned)p;
    hi = __shfl_down(hi, off, 64);
    lo = __shfl_down(lo, off, 64);
    return ((u64)hi << 32) | lo;
}
__device__ inline u64 shfl_u64(u64 p, int src) {
    unsigned hi = __shfl((unsigned)(p >> 32), src, 64);
    unsigned lo = __shfl((unsigned)p, src, 64);
    return ((u64)hi << 32) | lo;
}

// ---------------- init ---------------------------------------------------------
// ctr[0]=gCount ctr[1]=done ctr[2]=flag ctr[3]=eCount
__global__ void init_kernel(u64* bestC, u16* comp16, u32* deg, u32* ctr) {
    int i = blockIdx.x * blockDim.x + threadIdx.x;
    if (i < 8192) { bestC[i] = ~0ull; comp16[i] = (u16)i; deg[i] = 0; }
    if (i < 8) ctr[i] = 0;
}

// ---------------- Boruvka scan: key = w(32)<<26 | far(13)<<13 | near(13) -------
__global__ __launch_bounds__(256) void boruvka_scan(const float* __restrict__ dmat,
                                                    const u16* __restrict__ comp16,
                                                    u64* __restrict__ bestC,
                                                    const u32* __restrict__ ctr) {
    if (ctr[1]) return;
    int wave = threadIdx.x >> 6, lane = threadIdx.x & 63;
    int v = blockIdx.x * 4 + wave;
    u16 myc = comp16[v];
    const float4* row4 = (const float4*)(dmat + (size_t)v * N);
    const u64* c64 = (const u64*)comp16;
    u64 best = ~0ull;
    for (int k = 0; k < 32; k++) {
        int i4 = k * 64 + lane;
        float4 f = row4[i4];
        u64 c4 = c64[i4];
        int j0 = i4 * 4;
        float fv[4] = {f.x, f.y, f.z, f.w};
        #pragma unroll
        for (int e = 0; e < 4; e++) {
            if ((u16)(c4 >> (16 * e)) != myc) {
                u64 key = ((u64)__float_as_uint(fv[e]) << 26) | ((u64)(u32)(j0 + e) << 13) | (u32)v;
                best = key < best ? key : best;
            }
        }
    }
    #pragma unroll
    for (int off = 32; off; off >>= 1) {
        u64 q = shfl_down_u64(best, off);
        best = q < best ? q : best;
    }
    if (lane == 0 && best != ~0ull) atomicMin(&bestC[myc], best);
}

// ---------------- Boruvka merge (single bestC slice, self-resetting) -----------
__global__ __launch_bounds__(1024) void boruvka_merge(u16* comp16, u64* bestC,
                                                      u64* mstKeys, u32* ctr) {
    __shared__ u16 ping[8192], pong[8192];
    __shared__ unsigned char act[8192];
    __shared__ u32 cnt_s;
    if (ctr[1]) return;
    int t = threadIdx.x;
    if (t == 0) cnt_s = 0;
    for (int c = t; c < 8192; c += 1024) {
        u64 key = bestC[c];
        u16 par = (u16)c;
        if (key != ~0ull) {
            int far = (int)((key >> 13) & 8191);
            u16 cv = comp16[far];
            u64 k2 = bestC[cv];
            bool mutual = (k2 != ~0ull) && (comp16[(k2 >> 13) & 8191] == (u16)c);
            par = cv;
            if (mutual && (u32)c < (u32)cv) par = (u16)c;
            bool add = (!mutual) || ((u32)c < (u32)cv);
            if (add) {
                u32 idx = atomicAdd(&ctr[0], 1u);
                if (idx < 8192u) mstKeys[idx] = key;
            }
        }
        ping[c] = par;
        act[c] = 0;
    }
    __syncthreads();
    for (int c = t; c < 8192; c += 1024) bestC[c] = ~0ull;   // reset for next round
    __syncthreads();
    for (int it = 0; it < 13; it++) {
        for (int c = t; c < 8192; c += 1024) pong[c] = ping[ping[c]];
        __syncthreads();
        for (int c = t; c < 8192; c += 1024) ping[c] = pong[c];
        __syncthreads();
    }
    for (int v = t; v < 8192; v += 1024) {
        u16 nc = ping[comp16[v]];
        comp16[v] = nc;
        act[nc] = 1;
    }
    __syncthreads();
    u32 local = 0;
    for (int c = t; c < 8192; c += 1024) local += act[c];
    atomicAdd(&cnt_s, local);
    __syncthreads();
    if (t == 0 && cnt_s == 1) ctr[1] = 1;
}

// ---------------- bitonic sort of MST keys -> sorted weight bit-patterns -------
__global__ __launch_bounds__(1024) void sort_kernel(const u64* __restrict__ mstKeys,
                                                    u32* __restrict__ sortedWB,
                                                    u32* __restrict__ ctr) {
    __shared__ u64 keys[8192];
    int t = threadIdx.x;
    if (t == 0 && ctr[0] != 8191u) atomicOr(&ctr[2], 4u);
    for (int i = t; i < 8192; i += 1024) keys[i] = (i < 8191) ? mstKeys[i] : ~0ull;
    __syncthreads();
    for (u32 k = 2; k <= 8192; k <<= 1)
        for (u32 j = k >> 1; j > 0; j >>= 1) {
            for (int i = t; i < 8192; i += 1024) {
                u32 ixj = (u32)i ^ j;
                if (ixj > (u32)i) {
                    u64 a = keys[i], b = keys[ixj];
                    bool up = ((i & k) == 0);
                    if ((a > b) == up) { keys[i] = b; keys[ixj] = a; }
                }
            }
            __syncthreads();
        }
    for (int i = t; i < 8192; i += 1024) sortedWB[i] = (u32)(keys[i] >> 26);
}

// ---------------- collect G' = all edges whose value is an MST weight ----------
__global__ __launch_bounds__(256) void collect_kernel(const float* __restrict__ dmat,
                                                      const u32* __restrict__ sortedWB,
                                                      u64* __restrict__ edges,
                                                      u32* __restrict__ ctr) {
    __shared__ u32 sw[8192];
    int t = threadIdx.x;
    for (int i = t; i < 8192; i += 256) sw[i] = sortedWB[i];
    __syncthreads();
    u32 wmin = sw[0], wmax = sw[8190];
    int row0 = blockIdx.x * 8;
    for (int r = 0; r < 8; r++) {
        int i = row0 + r;
        const float4* row4 = (const float4*)(dmat + (size_t)i * N);
        for (int c4 = t; c4 < 2048; c4 += 256) {
            float4 f = row4[c4];
            int j0 = c4 * 4;
            float fv[4] = {f.x, f.y, f.z, f.w};
            #pragma unroll
            for (int e = 0; e < 4; e++) {
                int j = j0 + e;
                if (j <= i) continue;
                u32 wb = __float_as_uint(fv[e]);
                if (wb < wmin || wb > wmax) continue;
                int lo = 0, hi = 8191;
                while (lo < hi) { int mid = (lo + hi) >> 1; if (sw[mid] < wb) lo = mid + 1; else hi = mid; }
                if (sw[lo] == wb) {
                    u32 idx = atomicAdd(&ctr[3], 1u);
                    if (idx < CAP_E) edges[idx] = ((u64)wb << 26) | ((u64)(u32)i << 13) | (u32)j;
                    else atomicOr(&ctr[2], 16u);
                }
            }
        }
    }
}

// ---------------- degree count -------------------------------------------------
__global__ void degcnt_kernel(const u64* __restrict__ edges, u32* __restrict__ deg,
                              const u32* __restrict__ ctr) {
    u32 m = ctr[3]; if (m > CAP_E) m = CAP_E;
    u32 idx = blockIdx.x * blockDim.x + threadIdx.x;
    if (idx < m) {
        u64 e = edges[idx];
        atomicAdd(&deg[(u32)(e >> 13) & 8191u], 1u);
        atomicAdd(&deg[(u32)e & 8191u], 1u);
    }
}

// ---------------- prefix sum -> packed offsets (off<<12 | deg) -----------------
__global__ __launch_bounds__(1024) void offs_kernel(const u32* __restrict__ deg,
                                                    u32* __restrict__ offsP,
                                                    u32* __restrict__ cur,
                                                    u32* __restrict__ ctr) {
    __shared__ u32 partial[1024];
    int t = threadIdx.x;
    u32 loc[8], s = 0;
    #pragma unroll
    for (int e = 0; e < 8; e++) { loc[e] = deg[t * 8 + e]; s += loc[e]; }
    partial[t] = s;
    __syncthreads();
    for (int d = 1; d < 1024; d <<= 1) {
        u32 v = (t >= d) ? partial[t - d] : 0;
        __syncthreads();
        partial[t] += v;
        __syncthreads();
    }
    u32 run = t ? partial[t - 1] : 0;
    #pragma unroll
    for (int e = 0; e < 8; e++) {
        u32 d = loc[e];
        if (d > 4095u) atomicOr(&ctr[2], 32u);
        offsP[t * 8 + e] = (run << 12) | (d & 4095u);
        cur[t * 8 + e] = run;
        run += d;
    }
}

// ---------------- fill adjacency: entry = wbits(32)<<13 | far(13) --------------
__global__ void fill_kernel(const u64* __restrict__ edges, u32* __restrict__ cur,
                            u64* __restrict__ adj, const u32* __restrict__ ctr) {
    u32 m = ctr[3]; if (m > CAP_E) m = CAP_E;
    u32 idx = blockIdx.x * blockDim.x + threadIdx.x;
    if (idx < m) {
        u64 e = edges[idx];
        u32 wb = (u32)(e >> 26);
        u32 i = (u32)(e >> 13) & 8191u, j = (u32)e & 8191u;
        u32 p1 = atomicAdd(&cur[i], 1u); adj[p1] = ((u64)wb << 13) | j;
        u32 p2 = atomicAdd(&cur[j], 1u); adj[p2] = ((u64)wb << 13) | i;
    }
}

// ---------------- exact sparse Prim on G' (single wave) ------------------------
// mind in LDS, transposed: vertex k -> sMind[(k&63)*128 + (k>>6)]; per-lane
// cached packed min (wbits<<13 | k); pop = 6-level shuffle argmin (value, index).
__global__ __launch_bounds__(64) void gprim_kernel(const u32* __restrict__ offsP,
                                                   const u64* __restrict__ adj,
                                                   float* __restrict__ out,
                                                   u32* __restrict__ seqv,
                                                   u32* __restrict__ ctr) {
    __shared__ u32 sOffs[8192];
    __shared__ u32 sMind[8192];
    const int lane = threadIdx.x;
    for (int i = lane; i < 8192; i += 64) sOffs[i] = offsP[i];
    for (int i = lane; i < 8192; i += 64) sMind[i] = 0xFFFFFFFFu;
    __syncthreads();

    u64 ins0 = 0, ins1 = 0;          // inserted bits for this lane's 128 slots
    u64 cmin = ~0ull;                // packed min over live slots
    const u64 INFP = ((u64)0xFFFFFFFFull << 13);

    auto insert_vertex = [&](u32 v) {
        int L = (int)(v & 63u);
        if (lane == L) {
            int slot = (int)(v >> 6);
            if (slot < 64) ins0 |= 1ull << slot; else ins1 |= 1ull << (slot - 64);
            sMind[L * 128 + slot] = 0xFFFFFFFFu;
        }
        // cooperative rescan of owner's 128 slots (contiguous, conflict-free)
        u64 two = *(const u64*)&sMind[L * 128 + 2 * lane];
        u32 a = (u32)two, b = (u32)(two >> 32);
        u64 pa = ((u64)a << 13) | (u32)((2 * lane) * 64 + L);
        u64 pb = ((u64)b << 13) | (u32)((2 * lane + 1) * 64 + L);
        u64 pm = pa < pb ? pa : pb;
        #pragma unroll
        for (int off = 32; off; off >>= 1) {
            u64 q = shfl_down_u64(pm, off);
            pm = q < pm ? q : pm;
        }
        pm = shfl_u64(pm, 0);
        if (lane == L) cmin = pm;
        // offer v's adjacency
        u32 op = sOffs[v];
        u32 o = op >> 12, dg = op & 4095u;
        for (u32 k = 0; k < dg; k++) {
            u64 e = adj[o + k];
            u32 far = (u32)e & 8191u;
            u32 wb = (u32)(e >> 13);
            if ((int)(far & 63u) == lane) {
                int slot = (int)(far >> 6);
                bool ins = (slot < 64) ? ((ins0 >> slot) & 1ull) : ((ins1 >> (slot - 64)) & 1ull);
                if (!ins) {
                    int loc = lane * 128 + slot;
                    u32 curv = sMind[loc];
                    if (wb < curv) {
                        sMind[loc] = wb;
                        u64 pk = ((u64)wb << 13) | far;
                        if (pk < cmin) cmin = pk;
                    }
                }
            }
        }
    };

    insert_vertex(0);
    for (int step = 0; step < N - 1; ++step) {
        u64 p = cmin;
        #pragma unroll
        for (int off = 32; off; off >>= 1) {
            u64 q = shfl_down_u64(p, off);
            p = q < p ? q : p;
        }
        p = shfl_u64(p, 0);
        if (p >= INFP) { if (lane == 0) atomicOr(&ctr[2], 2u); break; }
        u32 v = (u32)(p & 8191u);
        u32 wb = (u32)(p >> 13);
        if (lane == 0) { out[2 * step + 1] = __uint_as_float(wb); seqv[step] = v; }
        insert_vertex(v);
    }
}

// ---------------- exact verifier (dense recurrence check) ----------------------
__global__ __launch_bounds__(128) void verify_kernel(const float* __restrict__ dmat,
                                                     const u32* __restrict__ seqv,
                                                     const float* __restrict__ out,
                                                     u32* __restrict__ ctr) {
    __shared__ u32 sseq[8192];
    __shared__ u32 sdeath[8192];
    int t = threadIdx.x;
    for (int i = t; i < 8191; i += 128) {
        sseq[i] = seqv[i] & 8191u;
        sdeath[i] = __float_as_uint(out[2 * i + 1]);
    }
    __syncthreads();
    int j = blockIdx.x * 128 + t;
    float mj = dmat[j];
    bool inserted = (j == 0);
    u32 bad = 0;
    for (int s = 0; s < 8191; s++) {
        u32 vt = sseq[s];
        u32 wbits = sdeath[s];
        float w = __uint_as_float(wbits);
        if (!inserted) {
            if ((int)vt == j) {
                if (__float_as_uint(mj) != wbits) bad = 1;
                inserted = true;
            } else {
                if (mj < w || (mj == w && j < (int)vt)) bad = 1;
            }
        }
        float dv = dmat[(size_t)vt * N + j];
        mj = dv < mj ? dv : mj;
    }
    if (!inserted) bad = 1;
    if (bad) atomicOr(&ctr[2], 1u);
}

// ---------------- dense exact Prim (R2-proven body) ----------------------------
__device__ inline void dense_prim_body(const float* __restrict__ dmat, float* __restrict__ out) {
    const int t    = threadIdx.x;
    const int lane = t & 63;
    const int wave = t >> 6;
    __shared__ u64 red[2][16];

    float mind[8];
    {
        float4 r0 = *(const float4*)(dmat + t * 8);
        float4 r1 = *(const float4*)(dmat + t * 8 + 4);
        mind[0] = r0.x; mind[1] = r0.y; mind[2] = r0.z; mind[3] = r0.w;
        mind[4] = r1.x; mind[5] = r1.y; mind[6] = r1.z; mind[7] = r1.w;
    }
    unsigned mask = (t == 0) ? 1u : 0u;

    for (int step = 0; step < N - 1; ++step) {
        u64 p = ~0ull;
        #pragma unroll
        for (int k = 0; k < 8; k++) {
            float v = ((mask >> k) & 1u) ? BIGF : mind[k];
            u64 q = ((u64)__float_as_uint(v) << 32) | (unsigned)(t * 8 + k);
            p = q < p ? q : p;
        }
        #pragma unroll
        for (int off = 32; off; off >>= 1) {
            u64 q = shfl_down_u64(p, off);
            p = q < p ? q : p;
        }
        if (lane == 0) red[step & 1][wave] = p;
        __syncthreads();
        u64 m = red[step & 1][0];
        #pragma unroll
        for (int w = 1; w < 16; w++) {
            u64 q = red[step & 1][w];
            m = q < m ? q : m;
        }
        int j = (int)(unsigned)m;
        if (t == 0) out[2 * step + 1] = __uint_as_float((unsigned)(m >> 32));
        if ((j >> 3) == t) mask |= 1u << (j & 7);

        const float* row = dmat + (size_t)j * N + t * 8;
        float4 r0 = *(const float4*)(row);
        float4 r1 = *(const float4*)(row + 4);
        float dv[8] = {r0.x, r0.y, r0.z, r0.w, r1.x, r1.y, r1.z, r1.w};
        #pragma unroll
        for (int k = 0; k < 8; k++) mind[k] = dv[k] < mind[k] ? dv[k] : mind[k];
    }
}

__global__ __launch_bounds__(1024) void prim_exact_kernel(const float* __restrict__ dmat,
                                                          float* __restrict__ out) {
    dense_prim_body(dmat, out);
}

__global__ __launch_bounds__(1024) void prim_fallback_kernel(const float* __restrict__ dmat,
                                                             float* __restrict__ out,
                                                             const u32* __restrict__ ctr) {
    if (ctr[2] == 0u) return;
    dense_prim_body(dmat, out);
}

extern "C" void kernel_launch(void* const* d_in, const int* in_sizes, int n_in,
                              void* d_out, int out_size, void* d_ws, size_t ws_size,
                              hipStream_t stream) {
    const float* x = (const float*)d_in[0];
    float* out = (float*)d_out;

    char* ws = (char*)d_ws;
    float* dmat = (float*)ws;                      // 256 MiB
    size_t o = (size_t)N * N * 4;

    // aux layout (only used if ws_size permits)
    u64* bestC     = (u64*)(ws + o);   o += 8192 * 8;        // 64 KB
    u64* mstKeys   = (u64*)(ws + o);   o += 8192 * 8;        // 64 KB
    u16* comp16    = (u16*)(ws + o);   o += 8192 * 2;        // 16 KB
    u32* sortedWB  = (u32*)(ws + o);   o += 8192 * 4;        // 32 KB
    u32* deg       = (u32*)(ws + o);   o += 8192 * 4;        // 32 KB
    u32* offsP     = (u32*)(ws + o);   o += 8192 * 4;        // 32 KB
    u32* cur       = (u32*)(ws + o);   o += 8192 * 4;        // 32 KB
    u32* seqv      = (u32*)(ws + o);   o += 8192 * 4;        // 32 KB
    u32* ctr       = (u32*)(ws + o);   o += 256;
    u64* edges     = (u64*)(ws + o);   o += (size_t)CAP_E * 8;      // 4 MB
    u64* adj       = (u64*)(ws + o);   o += (size_t)CAP_E * 2 * 8;  // 8 MB
    const size_t need = o;

    zero_out_kernel<<<(out_size + 255) / 256, 256, 0, stream>>>(out, out_size);
    dist_kernel<<<dim3(N / 64, N / 64), 256, 0, stream>>>(x, dmat);

    if (ws_size >= need) {
        // ---- fast path: Boruvka MST -> weight set -> G' -> exact sparse Prim ----
        init_kernel<<<32, 256, 0, stream>>>(bestC, comp16, deg, ctr);
        for (int r = 0; r < 13; r++) {
            boruvka_scan<<<N / 4, 256, 0, stream>>>(dmat, comp16, bestC, ctr);
            boruvka_merge<<<1, 1024, 0, stream>>>(comp16, bestC, mstKeys, ctr);
        }
        sort_kernel<<<1, 1024, 0, stream>>>(mstKeys, sortedWB, ctr);
        collect_kernel<<<1024, 256, 0, stream>>>(dmat, sortedWB, edges, ctr);
        degcnt_kernel<<<(CAP_E + 255) / 256, 256, 0, stream>>>(edges, deg, ctr);
        offs_kernel<<<1, 1024, 0, stream>>>(deg, offsP, cur, ctr);
        fill_kernel<<<(CAP_E + 255) / 256, 256, 0, stream>>>(edges, cur, adj, ctr);
        gprim_kernel<<<1, 64, 0, stream>>>(offsP, adj, out, seqv, ctr);
        verify_kernel<<<64, 128, 0, stream>>>(dmat, seqv, out, ctr);
        prim_fallback_kernel<<<1, 1024, 0, stream>>>(dmat, out, ctr);
    } else {
        // ---- compact path (ws too small for aux): proven R2 pipeline ----
        prim_exact_kernel<<<1, 1024, 0, stream>>>(dmat, out);
    }
}

// Round 6
// 10130.916 us; speedup vs baseline: 1.1400x; 1.1338x over previous
//
#include <hip/hip_runtime.h>
#include <math.h>

#define N 8192
#define DIM 64
#define CAP_E 2000000

typedef unsigned long long u64;
typedef unsigned int u32;
typedef unsigned short u16;

// ---------------- zero the output buffer (births stay 0) -----------------------
__global__ void zero_out_kernel(float* __restrict__ out, int n) {
    int i = blockIdx.x * blockDim.x + threadIdx.x;
    if (i < n) out[i] = 0.0f;
}

// ---------------- canonical norms: ni = sum fmaf(x_k, x_k) ascending k ---------
__global__ __launch_bounds__(256) void norms_kernel(const float* __restrict__ x,
                                                    float* __restrict__ norms) {
    int i = blockIdx.x * blockDim.x + threadIdx.x;
    const float* row = x + (size_t)i * DIM;
    float acc = 0.f;
    #pragma unroll
    for (int k = 0; k < DIM; k++) { float v = row[k]; acc = __builtin_fmaf(v, v, acc); }
    norms[i] = acc;
}

// ---------------- canonical tile machinery (shared by scan & collect) ----------
// All distance computations in the whole pipeline go through tile_d2 with the
// SAME fmaf chain (ascending k) and the SAME pinned d2 = fmaf(-2, dot, ni+nj),
// guaranteeing bitwise-consistent d2 across kernels.
__device__ inline void stage_tiles(const float* __restrict__ x, int bi, int bj, int t,
                                   float (*As)[64], float (*Bs)[64]) {
    int r = t >> 2, c0 = (t & 3) * 16;
    const float4* pa = (const float4*)(x + (size_t)(bi * 64 + r) * DIM + c0);
    const float4* pb = (const float4*)(x + (size_t)(bj * 64 + r) * DIM + c0);
    #pragma unroll
    for (int q = 0; q < 4; q++) {
        float4 a = pa[q], b = pb[q];
        int c = c0 + q * 4;
        As[c + 0][r] = a.x; As[c + 1][r] = a.y; As[c + 2][r] = a.z; As[c + 3][r] = a.w;
        Bs[c + 0][r] = b.x; Bs[c + 1][r] = b.y; Bs[c + 2][r] = b.z; Bs[c + 3][r] = b.w;
    }
}

__device__ inline void tile_d2(const float (*As)[64], const float (*Bs)[64],
                               const float ni[4], const float nj[4],
                               int tx, int ty, u32 d2b[4][4]) {
    float acc[4][4] = {};
    #pragma unroll 4
    for (int k = 0; k < 64; k++) {
        float av[4], bv[4];
        #pragma unroll
        for (int r = 0; r < 4; r++) av[r] = As[k][ty * 4 + r];
        #pragma unroll
        for (int c = 0; c < 4; c++) bv[c] = Bs[k][tx * 4 + c];
        #pragma unroll
        for (int r = 0; r < 4; r++)
            #pragma unroll
            for (int c = 0; c < 4; c++)
                acc[r][c] = __builtin_fmaf(av[r], bv[c], acc[r][c]);
    }
    #pragma unroll
    for (int r = 0; r < 4; r++)
        #pragma unroll
        for (int c = 0; c < 4; c++) {
            float d2 = __builtin_fmaf(-2.0f, acc[r][c], ni[r] + nj[c]);
            d2 = d2 < 0.f ? 0.f : d2;
            d2b[r][c] = __float_as_uint(d2);
        }
}

// ---------------- init ---------------------------------------------------------
// ctr[0]=mstCount ctr[1]=done ctr[2]=flag ctr[3]=edgeCount
__global__ void init_kernel(u64* bestR, u64* bestC, u16* comp16, u32* deg, u32* ctr) {
    int i = blockIdx.x * blockDim.x + threadIdx.x;
    if (i < 8192) { bestR[i] = ~0ull; bestC[i] = ~0ull; comp16[i] = (u16)i; deg[i] = 0; }
    if (i < 8) ctr[i] = 0;
}

// ---------------- Boruvka fused scan: recompute tile + per-row best ------------
// key = d2bits(32)<<26 | lo(13)<<13 | hi(13)  (orientation-independent -> the
// hooking pointer graph has only 2-cycles, standard Boruvka correctness)
__global__ __launch_bounds__(256) void scan_fused(const float* __restrict__ x,
                                                  const float* __restrict__ norms,
                                                  const u16* __restrict__ comp16,
                                                  u64* __restrict__ bestR,
                                                  const u32* __restrict__ ctr) {
    if (ctr[1]) return;
    int bi = blockIdx.y, bj = blockIdx.x;
    if (bj < bi) return;
    __shared__ float As[64][64], Bs[64][64];
    __shared__ u16 rc[64], cc[64];
    __shared__ u64 rowBest[64], colBest[64];
    int t = threadIdx.x;
    stage_tiles(x, bi, bj, t, As, Bs);
    if (t < 64) {
        rc[t] = comp16[bi * 64 + t];
        cc[t] = comp16[bj * 64 + t];
        rowBest[t] = ~0ull; colBest[t] = ~0ull;
    }
    __syncthreads();
    int tx = t & 15, ty = t >> 4;
    float ni[4], nj[4];
    #pragma unroll
    for (int r = 0; r < 4; r++) ni[r] = norms[bi * 64 + ty * 4 + r];
    #pragma unroll
    for (int c = 0; c < 4; c++) nj[c] = norms[bj * 64 + tx * 4 + c];
    u32 d2b[4][4];
    tile_d2(As, Bs, ni, nj, tx, ty, d2b);

    #pragma unroll
    for (int r = 0; r < 4; r++) {
        u16 rcv = rc[ty * 4 + r];
        int gi = bi * 64 + ty * 4 + r;
        u64 best = ~0ull;
        #pragma unroll
        for (int c = 0; c < 4; c++) {
            if (cc[tx * 4 + c] != rcv) {
                int gj = bj * 64 + tx * 4 + c;
                u32 lo = gi < gj ? (u32)gi : (u32)gj;
                u32 hi = gi < gj ? (u32)gj : (u32)gi;
                u64 key = ((u64)d2b[r][c] << 26) | ((u64)lo << 13) | hi;
                if (key < best) best = key;
            }
        }
        if (best != ~0ull) atomicMin(&rowBest[ty * 4 + r], best);
    }
    #pragma unroll
    for (int c = 0; c < 4; c++) {
        u16 ccv = cc[tx * 4 + c];
        int gj = bj * 64 + tx * 4 + c;
        u64 best = ~0ull;
        #pragma unroll
        for (int r = 0; r < 4; r++) {
            if (rc[ty * 4 + r] != ccv) {
                int gi = bi * 64 + ty * 4 + r;
                u32 lo = gi < gj ? (u32)gi : (u32)gj;
                u32 hi = gi < gj ? (u32)gj : (u32)gi;
                u64 key = ((u64)d2b[r][c] << 26) | ((u64)lo << 13) | hi;
                if (key < best) best = key;
            }
        }
        if (best != ~0ull) atomicMin(&colBest[tx * 4 + c], best);
    }
    __syncthreads();
    if (t < 64) {
        if (rowBest[t] != ~0ull) atomicMin(&bestR[bi * 64 + t], rowBest[t]);
        if (colBest[t] != ~0ull) atomicMin(&bestR[bj * 64 + t], colBest[t]);
    }
}

// ---------------- fold rows -> components --------------------------------------
__global__ void fold_kernel(u64* bestR, u64* bestC, const u16* comp16, const u32* ctr) {
    if (ctr[1]) return;
    int i = blockIdx.x * blockDim.x + threadIdx.x;
    if (i < 8192) {
        u64 k = bestR[i];
        if (k != ~0ull) { atomicMin(&bestC[comp16[i]], k); bestR[i] = ~0ull; }
    }
}

// ---------------- Boruvka merge ------------------------------------------------
__global__ __launch_bounds__(1024) void merge_kernel(u16* comp16, u64* bestC,
                                                     u64* mstKeys, u32* ctr) {
    __shared__ u16 ping[8192], pong[8192];
    __shared__ unsigned char act[8192];
    __shared__ u32 cnt_s;
    if (ctr[1]) return;
    int t = threadIdx.x;
    if (t == 0) cnt_s = 0;
    for (int c = t; c < 8192; c += 1024) {
        u64 key = bestC[c];
        u16 par = (u16)c;
        if (key != ~0ull) {
            u32 a = (u32)(key >> 13) & 8191u, b = (u32)key & 8191u;
            u16 ca = comp16[a];
            u16 cv = (ca == (u16)c) ? comp16[b] : ca;
            u64 k2 = bestC[cv];
            bool mutual = false;
            if (k2 != ~0ull) {
                u32 a2 = (u32)(k2 >> 13) & 8191u, b2 = (u32)k2 & 8191u;
                u16 ca2 = comp16[a2];
                u16 cv2 = (ca2 == cv) ? comp16[b2] : ca2;
                mutual = (cv2 == (u16)c);
            }
            par = cv;
            if (mutual && (u32)c < (u32)cv) par = (u16)c;
            bool add = (!mutual) || ((u32)c < (u32)cv);
            if (add) {
                u32 idx = atomicAdd(&ctr[0], 1u);
                if (idx < 8192u) mstKeys[idx] = key;
            }
        }
        ping[c] = par;
        act[c] = 0;
    }
    __syncthreads();
    for (int c = t; c < 8192; c += 1024) bestC[c] = ~0ull;   // reset for next round
    __syncthreads();
    for (int it = 0; it < 13; it++) {
        for (int c = t; c < 8192; c += 1024) pong[c] = ping[ping[c]];
        __syncthreads();
        for (int c = t; c < 8192; c += 1024) ping[c] = pong[c];
        __syncthreads();
    }
    for (int v = t; v < 8192; v += 1024) {
        u16 nc = ping[comp16[v]];
        comp16[v] = nc;
        act[nc] = 1;
    }
    __syncthreads();
    u32 local = 0;
    for (int c = t; c < 8192; c += 1024) local += act[c];
    atomicAdd(&cnt_s, local);
    __syncthreads();
    if (t == 0 && cnt_s == 1) ctr[1] = 1;
}

// ---------------- bitonic sort -> sorted d2 bit-patterns -----------------------
__global__ __launch_bounds__(1024) void sort_kernel(const u64* __restrict__ mstKeys,
                                                    u32* __restrict__ sortedWB,
                                                    const u32* __restrict__ ctr) {
    __shared__ u64 keys[8192];
    int t = threadIdx.x;
    u32 m = ctr[0]; if (m > 8191u) m = 8191u;
    for (int i = t; i < 8192; i += 1024) keys[i] = (i < (int)m) ? mstKeys[i] : ~0ull;
    __syncthreads();
    for (u32 k = 2; k <= 8192; k <<= 1)
        for (u32 j = k >> 1; j > 0; j >>= 1) {
            for (int i = t; i < 8192; i += 1024) {
                u32 ixj = (u32)i ^ j;
                if (ixj > (u32)i) {
                    u64 a = keys[i], b = keys[ixj];
                    bool up = ((i & k) == 0);
                    if ((a > b) == up) { keys[i] = b; keys[ixj] = a; }
                }
            }
            __syncthreads();
        }
    for (int i = t; i < 8192; i += 1024)
        sortedWB[i] = (i < 8191) ? (u32)(keys[i] >> 26) : 0xFFFFFFFFu;
}

// ---------------- collect G' = all pairs whose d2 equals an MST weight ---------
// edge (u64): rank(13)<<26 | i(13)<<13 | j(13), i<j, rank = lower_bound index
__global__ __launch_bounds__(256) void collect_kernel(const float* __restrict__ x,
                                                      const float* __restrict__ norms,
                                                      const u32* __restrict__ sortedWB,
                                                      u64* __restrict__ edges,
                                                      u32* __restrict__ ctr) {
    __shared__ float As[64][64], Bs[64][64];
    __shared__ u32 sw[8191];
    int bi = blockIdx.y, bj = blockIdx.x;
    if (bj < bi) return;
    int t = threadIdx.x;
    stage_tiles(x, bi, bj, t, As, Bs);
    for (int i = t; i < 8191; i += 256) sw[i] = sortedWB[i];
    __syncthreads();
    u32 wmin = sw[0], wmax = sw[8190];
    int tx = t & 15, ty = t >> 4;
    float ni[4], nj[4];
    #pragma unroll
    for (int r = 0; r < 4; r++) ni[r] = norms[bi * 64 + ty * 4 + r];
    #pragma unroll
    for (int c = 0; c < 4; c++) nj[c] = norms[bj * 64 + tx * 4 + c];
    u32 d2b[4][4];
    tile_d2(As, Bs, ni, nj, tx, ty, d2b);

    #pragma unroll
    for (int r = 0; r < 4; r++) {
        int gi = bi * 64 + ty * 4 + r;
        #pragma unroll
        for (int c = 0; c < 4; c++) {
            int gj = bj * 64 + tx * 4 + c;
            if (gj <= gi) continue;
            u32 wb = d2b[r][c];
            if (wb < wmin || wb > wmax) continue;
            int lo = 0, hi = 8190;
            while (lo < hi) { int mid = (lo + hi) >> 1; if (sw[mid] < wb) lo = mid + 1; else hi = mid; }
            if (sw[lo] == wb) {
                u32 idx = atomicAdd(&ctr[3], 1u);
                if (idx < CAP_E)
                    edges[idx] = ((u64)(u32)lo << 26) | ((u64)(u32)gi << 13) | (u32)gj;
                else
                    atomicOr(&ctr[2], 16u);
            }
        }
    }
}

// ---------------- degree count -------------------------------------------------
__global__ void degcnt_kernel(const u64* __restrict__ edges, u32* __restrict__ deg,
                              const u32* __restrict__ ctr) {
    u32 m = ctr[3]; if (m > CAP_E) m = CAP_E;
    for (u32 idx = blockIdx.x * 256u + threadIdx.x; idx < m; idx += gridDim.x * 256u) {
        u64 e = edges[idx];
        atomicAdd(&deg[(u32)(e >> 13) & 8191u], 1u);
        atomicAdd(&deg[(u32)e & 8191u], 1u);
    }
}

// ---------------- prefix sum: offs[8193] + cur ---------------------------------
__global__ __launch_bounds__(1024) void offs_kernel(const u32* __restrict__ deg,
                                                    u32* __restrict__ offs,
                                                    u32* __restrict__ cur) {
    __shared__ u32 partial[1024];
    int t = threadIdx.x;
    u32 loc[8], s = 0;
    #pragma unroll
    for (int e = 0; e < 8; e++) { loc[e] = deg[t * 8 + e]; s += loc[e]; }
    partial[t] = s;
    __syncthreads();
    for (int d = 1; d < 1024; d <<= 1) {
        u32 v = (t >= d) ? partial[t - d] : 0;
        __syncthreads();
        partial[t] += v;
        __syncthreads();
    }
    u32 run = t ? partial[t - 1] : 0;
    #pragma unroll
    for (int e = 0; e < 8; e++) { offs[t * 8 + e] = run; cur[t * 8 + e] = run; run += loc[e]; }
    if (t == 1023) offs[8192] = run;
}

// ---------------- fill adjacency: entry = rank(13)<<13 | far(13) ---------------
__global__ void fill_kernel(const u64* __restrict__ edges, u32* __restrict__ cur,
                            u32* __restrict__ adj, const u32* __restrict__ ctr) {
    u32 m = ctr[3]; if (m > CAP_E) m = CAP_E;
    for (u32 idx = blockIdx.x * 256u + threadIdx.x; idx < m; idx += gridDim.x * 256u) {
        u64 e = edges[idx];
        u32 rk = (u32)(e >> 26) & 8191u;
        u32 i = (u32)(e >> 13) & 8191u, j = (u32)e & 8191u;
        u32 p1 = atomicAdd(&cur[i], 1u); adj[p1] = (rk << 13) | j;
        u32 p2 = atomicAdd(&cur[j], 1u); adj[p2] = (rk << 13) | i;
    }
}

// ---------------- exact sparse Prim on G' (single wave) ------------------------
// sMind[vertex] = u16 normalized rank (equal d2 -> equal rank, so (rank, far)
// order == reference's (value, index) argmin incl. first-occurrence ties).
// Per-lane cached min over its 128 owned vertices; pop = u32 shuffle reduce.
__global__ __launch_bounds__(64) void gprim_kernel(const u32* __restrict__ offs,
                                                   const u32* __restrict__ adjG,
                                                   u32* __restrict__ seqv,
                                                   u32* __restrict__ ctr) {
    __shared__ u16 sMind[8192];
    __shared__ u32 sOffs[8193];
    __shared__ u32 scratch[64];
    const int lane = threadIdx.x;
    for (int i = lane; i < 8192; i += 64) sMind[i] = 0xFFFF;
    for (int i = lane; i < 8193; i += 64) sOffs[i] = offs[i];
    __syncthreads();

    u64 ins0 = 0, ins1 = 0;
    u32 cmin = 0xFFFFFFFFu;
    const u32 INFP = 0xFFFFu << 13;

    u32 v = 0;
    for (int step = 0; step < N - 1; ++step) {
        // ---- insert v ----
        u32 o = sOffs[v], dg = sOffs[v + 1] - o;
        int L = (int)(v & 63u);
        if (lane == L) {
            int slot = (int)(v >> 6);
            if (slot < 64) ins0 |= 1ull << slot; else ins1 |= 1ull << (slot - 64);
            sMind[L * 128 + slot] = 0xFFFF;
        }
        __builtin_amdgcn_wave_barrier();
        for (u32 base = 0; base < dg; base += 64) {
            u32 kk = base + (u32)lane;
            u32 ev = 0xFFFFFFFFu;
            if (kk < dg) ev = adjG[o + kk];
            scratch[lane] = ev;
            __builtin_amdgcn_wave_barrier();
            u32 cnt = dg - base; if (cnt > 64) cnt = 64;
            for (u32 q = 0; q < cnt; q++) {
                u32 e = scratch[q];
                u32 far = e & 8191u, rk = e >> 13;
                if ((int)(far & 63u) == lane) {
                    int slot = (int)(far >> 6);
                    bool isin = (slot < 64) ? (((ins0 >> slot) & 1ull) != 0)
                                            : (((ins1 >> (slot - 64)) & 1ull) != 0);
                    if (!isin) {
                        int loc = lane * 128 + slot;
                        u32 cu = sMind[loc];
                        if (rk < cu) {
                            sMind[loc] = (u16)rk;
                            u32 pk = (rk << 13) | far;
                            if (pk < cmin) cmin = pk;
                        }
                    }
                }
            }
            __builtin_amdgcn_wave_barrier();
        }
        // ---- owner-row rescan (only lane L's cmin is invalidated by the pop) ----
        {
            u32 two = *(const u32*)&sMind[L * 128 + 2 * lane];
            u32 m0 = two & 0xFFFFu, m1 = two >> 16;
            u32 p0 = (m0 << 13) | (u32)((2 * lane) * 64 + L);
            u32 p1 = (m1 << 13) | (u32)((2 * lane + 1) * 64 + L);
            u32 pm = p0 < p1 ? p0 : p1;
            #pragma unroll
            for (int off = 32; off; off >>= 1) {
                u32 q = __shfl_down(pm, off, 64);
                pm = q < pm ? q : pm;
            }
            pm = __shfl(pm, 0, 64);
            if (lane == L) cmin = pm;
        }
        // ---- pop ----
        u32 p = cmin;
        #pragma unroll
        for (int off = 32; off; off >>= 1) {
            u32 q = __shfl_down(p, off, 64);
            p = q < p ? q : p;
        }
        p = __shfl(p, 0, 64);
        if (p >= INFP) { if (lane == 0) atomicOr(&ctr[2], 2u); break; }
        if (lane == 0) seqv[step] = p;
        v = p & 8191u;
    }
}

// ---------------- gather: deaths = sqrt(d2 of popped rank) ---------------------
__global__ void gather_kernel(const u32* __restrict__ seqv,
                              const u32* __restrict__ sortedWB,
                              float* __restrict__ out) {
    int s = blockIdx.x * blockDim.x + threadIdx.x;
    if (s < N - 1) {
        u32 p = seqv[s];
        u32 rk = p >> 13;
        out[2 * s + 1] = sqrtf(__uint_as_float(sortedWB[rk]));
    }
}

extern "C" void kernel_launch(void* const* d_in, const int* in_sizes, int n_in,
                              void* d_out, int out_size, void* d_ws, size_t ws_size,
                              hipStream_t stream) {
    const float* x = (const float*)d_in[0];
    float* out = (float*)d_out;

    char* ws = (char*)d_ws;
    size_t o = 0;
    u64* bestR    = (u64*)(ws + o); o += 8192 * 8;            // 64 KB
    u64* bestC    = (u64*)(ws + o); o += 8192 * 8;            // 64 KB
    u64* mstKeys  = (u64*)(ws + o); o += 8192 * 8;            // 64 KB
    u64* edges    = (u64*)(ws + o); o += (size_t)CAP_E * 8;   // 16 MB
    float* norms  = (float*)(ws + o); o += 8192 * 4;
    u32* sortedWB = (u32*)(ws + o); o += 8192 * 4;
    u32* deg      = (u32*)(ws + o); o += 8192 * 4;
    u32* offs     = (u32*)(ws + o); o += 8200 * 4;
    u32* cur      = (u32*)(ws + o); o += 8192 * 4;
    u32* seqv     = (u32*)(ws + o); o += 8192 * 4;
    u32* adj      = (u32*)(ws + o); o += (size_t)CAP_E * 2 * 4; // 16 MB
    u16* comp16   = (u16*)(ws + o); o += 8192 * 2;
    u32* ctr      = (u32*)(ws + o); o += 256;
    // total ~33 MB << 256 MiB

    zero_out_kernel<<<(out_size + 255) / 256, 256, 0, stream>>>(out, out_size);
    norms_kernel<<<32, 256, 0, stream>>>(x, norms);
    init_kernel<<<32, 256, 0, stream>>>(bestR, bestC, comp16, deg, ctr);

    for (int r = 0; r < 13; r++) {
        scan_fused<<<dim3(128, 128), 256, 0, stream>>>(x, norms, comp16, bestR, ctr);
        fold_kernel<<<32, 256, 0, stream>>>(bestR, bestC, comp16, ctr);
        merge_kernel<<<1, 1024, 0, stream>>>(comp16, bestC, mstKeys, ctr);
    }

    sort_kernel<<<1, 1024, 0, stream>>>(mstKeys, sortedWB, ctr);
    collect_kernel<<<dim3(128, 128), 256, 0, stream>>>(x, norms, sortedWB, edges, ctr);
    degcnt_kernel<<<512, 256, 0, stream>>>(edges, deg, ctr);
    offs_kernel<<<1, 1024, 0, stream>>>(deg, offs, cur);
    fill_kernel<<<512, 256, 0, stream>>>(edges, cur, adj, ctr);
    gprim_kernel<<<1, 64, 0, stream>>>(offs, adj, seqv, ctr);
    gather_kernel<<<32, 256, 0, stream>>>(seqv, sortedWB, out);
}